// Round 6
// baseline (303.707 us; speedup 1.0000x reference)
//
#include <hip/hip_runtime.h>

// Conv2d 3x3, cin=4, cout=4, pad=1, stride=1 on [4,4096,4096] fp32.
//
// Round-6: rolling-register column walk. Thread = 4-px column segment over
// 16 output rows, all 4 cout. Three rotating acc rows A,B,C (48 VGPR):
// input row `it` is loaded ONCE (4 cin x {1 dwordx4 + 2 halo dwords}) and
// feeds out[it-1] (tap r=2), out[it] (r=1), out[it+1] (r=0). 576 FMA per
// step vs 16 load instrs; addressing = 1 v_add per step (saddr-form loads).
// Rotation via static names (3 calls per loop iter), #pragma unroll 1 keeps
// the body I$-resident. Grid 1024 = 4 blocks/CU exactly; launch_bounds
// (256,4) caps VGPR at 128 -> 4 waves/SIMD, all blocks resident, no tail.

#define IW 4096
#define IH 4096
constexpr long long HWsz = (long long)IH * IW;

typedef float v4f __attribute__((ext_vector_type(4)));

struct Acc { float a[4][4]; };   // [cout][px]

template <typename T>
__device__ __forceinline__ void conv_step(
    Acc& A, Acc& B, Acc& C,                 // out[it-1], out[it], out[it+1]
    const float* __restrict__ xin,
    const float* __restrict__ wt,
    float* __restrict__ out,
    int it, int y0, int gx, bool x_lo, bool x_hi, T /*tag*/)
{
    // ---- load input row `it` for all 4 cin (zeros outside the image) ----
    float v[4][6];
    if (it >= 0 && it < IH) {               // wave-uniform
        const int idx = it * IW + gx;       // element offset within a plane
        #pragma unroll
        for (int ci = 0; ci < 4; ++ci) {
            const float* p = xin + (long long)ci * HWsz;
            const v4f m = *reinterpret_cast<const v4f*>(p + idx);
            v[ci][1] = m.x; v[ci][2] = m.y; v[ci][3] = m.z; v[ci][4] = m.w;
            v[ci][0] = x_lo ? 0.f : p[idx - 1];   // masked at image edge
            v[ci][5] = x_hi ? 0.f : p[idx + 4];
        }
    } else {
        #pragma unroll
        for (int ci = 0; ci < 4; ++ci)
            #pragma unroll
            for (int j = 0; j < 6; ++j) v[ci][j] = 0.f;
    }

    // ---- fresh accumulator starts at zero ----
    #pragma unroll
    for (int co = 0; co < 4; ++co)
        #pragma unroll
        for (int p = 0; p < 4; ++p) C.a[co][p] = 0.f;

    // ---- FMAs: row `it` -> A (r=2), B (r=1), C (r=0) ----
    #pragma unroll
    for (int ci = 0; ci < 4; ++ci) {
        #pragma unroll
        for (int co = 0; co < 4; ++co) {
            #pragma unroll
            for (int kx = 0; kx < 3; ++kx) {
                const float w2 = wt[((co * 4 + ci) * 3 + 2) * 3 + kx];
                const float w1 = wt[((co * 4 + ci) * 3 + 1) * 3 + kx];
                const float w0 = wt[((co * 4 + ci) * 3 + 0) * 3 + kx];
                #pragma unroll
                for (int p = 0; p < 4; ++p) {
                    A.a[co][p] = fmaf(w2, v[ci][p + kx], A.a[co][p]);
                    B.a[co][p] = fmaf(w1, v[ci][p + kx], B.a[co][p]);
                    C.a[co][p] = fmaf(w0, v[ci][p + kx], C.a[co][p]);
                }
            }
        }
    }

    // ---- A = out[it-1] is complete: store (gated, wave-uniform) ----
    if (it - 1 >= y0) {                     // it-1 <= y0+15 by loop range
        const long long obase = (long long)(it - 1) * IW + gx;
        #pragma unroll
        for (int co = 0; co < 4; ++co) {
            v4f ov;
            ov.x = A.a[co][0]; ov.y = A.a[co][1];
            ov.z = A.a[co][2]; ov.w = A.a[co][3];
            *reinterpret_cast<v4f*>(out + co * HWsz + obase) = ov;
        }
    }
}

__global__ __launch_bounds__(256, 4) void conv3x3_kernel(
    const float* __restrict__ xin,   // [4][4096][4096]
    const float* __restrict__ wt,    // [4][4][3][3]
    float* __restrict__ out)         // [4][4096][4096]
{
    // grid = 4 x-strips * 256 y-segments = 1024 blocks; XCD-bijective swizzle
    // (1024 % 8 == 0): each XCD owns 32 consecutive y-segments = a 512-row band.
    const int bid = blockIdx.x;
    const int swz = (bid & 7) * 128 + (bid >> 3);
    const int by  = swz >> 2;                        // 0..255
    const int bx  = swz & 3;                         // 0..3
    const int y0  = by << 4;                         // 16 output rows
    const int gx  = bx * 1024 + (int)threadIdx.x * 4;

    const bool x_lo = (gx == 0);
    const bool x_hi = (gx + 4 == IW);

    Acc A, B, C;
    #pragma unroll
    for (int co = 0; co < 4; ++co)
        #pragma unroll
        for (int p = 0; p < 4; ++p) {
            A.a[co][p] = 0.f; B.a[co][p] = 0.f; C.a[co][p] = 0.f;
        }

    // 18 input rows: it = y0-1 .. y0+16, rotation period 3 -> 6 iterations.
    int it = y0 - 1;
    #pragma unroll 1
    for (int s = 0; s < 6; ++s) {
        conv_step(A, B, C, xin, wt, out, it,     y0, gx, x_lo, x_hi, 0);
        conv_step(B, C, A, xin, wt, out, it + 1, y0, gx, x_lo, x_hi, 0);
        conv_step(C, A, B, xin, wt, out, it + 2, y0, gx, x_lo, x_hi, 0);
        it += 3;
    }
}

extern "C" void kernel_launch(void* const* d_in, const int* in_sizes, int n_in,
                              void* d_out, int out_size, void* d_ws, size_t ws_size,
                              hipStream_t stream) {
    const float* xin = (const float*)d_in[0];
    const float* wt  = (const float*)d_in[1];
    float* out       = (float*)d_out;

    dim3 grid(1024), block(256);
    hipLaunchKernelGGL(conv3x3_kernel, grid, block, 0, stream, xin, wt, out);
}